// Round 5
// baseline (482.765 us; speedup 1.0000x reference)
//
#include <hip/hip_runtime.h>

#define NN 50000
#define NE 800000

// ---- bf16 helpers (manual RNE; values are finite) --------------------------
__device__ inline unsigned short f2bf(float f) {
    unsigned u = __float_as_uint(f);
    unsigned r = (u + 0x7FFFu + ((u >> 16) & 1u)) >> 16;
    return (unsigned short)r;
}
__device__ inline float bf2f(unsigned short h) {
    return __uint_as_float(((unsigned)h) << 16);
}

// X is stored as TWO column planes: plane p holds cols [32p, 32p+32) for all
// rows, contiguously: Xh[p*NN*32 + row*32 + (col-32p)]. Each 3.2MB plane fits
// a 4MiB per-XCD L2, so a column-half gather pass runs out of L2 instead of
// L3 (the 6.4MB row-major table missed L2 on every XCD).
__device__ inline void store_x_plane(unsigned short* Xh, int r, int col, ushort4 h) {
    unsigned short* plane = Xh + (size_t)(col >> 5) * ((size_t)NN * 32);
    *reinterpret_cast<ushort4*>(plane + (size_t)r * 32 + (col & 31)) = h;
}

// ---- fused: degree/cursor atomics + proj0 (feat @ W0, UNscaled) ------------
// Degree role is memory-side atomic-RMW bound (~33B/atomic of HBM traffic at
// ~650GB/s; in-flight depth doesn't matter, r3/r4). proj0 rides along on the
// otherwise-idle CUs. Role by blockIdx: bid%3==0 -> degree block (391 blocks,
// 2048 edges, 8/thread), else proj tile (782). dout_is scaling lives in
// gather-0 ((s*x)@W == s*(x@W)). Block 1 also zeroes the scan-sync words.
__global__ __launch_bounds__(256) void fused_build_proj0_kernel(
    const float* __restrict__ A,          // feat, lda=256
    const float* __restrict__ W,          // 256x64 row-major
    unsigned short* __restrict__ Xh,      // bf16 out, 2 planes [NN][32]
    const int* __restrict__ src, const int* __restrict__ dst,
    int* __restrict__ dout_cnt, int* __restrict__ cursor,
    int* __restrict__ epos, int* __restrict__ sync) {
    __shared__ float sAT[64 * 68];  // [k][row], pitch 68
    __shared__ float sW[64 * 64];   // [k][col]

    const int bid = blockIdx.x;
    if (bid % 3 == 0) {
        // ---- degree / CSR-slot role: 8 edges per thread, atomics unrolled --
        if (bid == 3 && threadIdx.x == 0) { sync[0] = 0; sync[1] = 0; }
        const int d = bid / 3;                  // 0..390
        const int e0 = d * 2048 + threadIdx.x;  // stride-256 over 8 slots
        int s[8], dn[8], p[8];
#pragma unroll
        for (int j = 0; j < 8; ++j) {
            int e = e0 + j * 256;
            if (e < NE) { s[j] = src[e]; dn[j] = dst[e]; } else dn[j] = -1;
        }
#pragma unroll
        for (int j = 0; j < 8; ++j)
            if (dn[j] >= 0) p[j] = atomicAdd(&cursor[dn[j]], 1);
#pragma unroll
        for (int j = 0; j < 8; ++j)
            if (dn[j] >= 0) atomicAdd(&dout_cnt[s[j]], 1);
#pragma unroll
        for (int j = 0; j < 8; ++j) {
            int e = e0 + j * 256;
            if (e < NE) epos[e] = p[j];
        }
        return;
    }
    if (bid == 1 && threadIdx.x == 0) { /* covered by bid==3 path above */ }

    // ---- proj role: 64x64 tile of X = feat @ W0 (no scale) ----
    const int p = bid - bid / 3 - 1;          // tile id 0..781
    constexpr int lda = 256;
    constexpr int KC = 64;
    constexpr int NCHUNK = 4;                 // K = 256
    float acc[4][4] = {};

    const int t = threadIdx.x;
    const int tx = t & 15;
    const int ty = t >> 4;
    const int row0 = p * 64;

    const int srow = t & 63;
    const int f0 = t >> 6;
    int grow = row0 + srow;
    if (grow > NN - 1) grow = NN - 1;         // clamp: loads always in-bounds
    const float* arow = A + (size_t)grow * lda;

    for (int kc = 0; kc < NCHUNK; ++kc) {
#pragma unroll
        for (int it = 0; it < 4; ++it) {
            int k = (f0 + it * 4) * 4;
            float4 a4 = *reinterpret_cast<const float4*>(arow + kc * KC + k);
            sAT[(k + 0) * 68 + srow] = a4.x;
            sAT[(k + 1) * 68 + srow] = a4.y;
            sAT[(k + 2) * 68 + srow] = a4.z;
            sAT[(k + 3) * 68 + srow] = a4.w;
        }
        {
            const float4* wsrc = reinterpret_cast<const float4*>(W + (size_t)kc * KC * 64);
            float4* wdst = reinterpret_cast<float4*>(sW);
#pragma unroll
            for (int it = 0; it < 4; ++it) wdst[t + it * 256] = wsrc[t + it * 256];
        }
        __syncthreads();
#pragma unroll 8
        for (int k = 0; k < KC; ++k) {
            float4 av = *reinterpret_cast<const float4*>(&sAT[k * 68 + ty * 4]);
            float4 wv = *reinterpret_cast<const float4*>(&sW[k * 64 + tx * 4]);
            acc[0][0] = fmaf(av.x, wv.x, acc[0][0]);
            acc[0][1] = fmaf(av.x, wv.y, acc[0][1]);
            acc[0][2] = fmaf(av.x, wv.z, acc[0][2]);
            acc[0][3] = fmaf(av.x, wv.w, acc[0][3]);
            acc[1][0] = fmaf(av.y, wv.x, acc[1][0]);
            acc[1][1] = fmaf(av.y, wv.y, acc[1][1]);
            acc[1][2] = fmaf(av.y, wv.z, acc[1][2]);
            acc[1][3] = fmaf(av.y, wv.w, acc[1][3]);
            acc[2][0] = fmaf(av.z, wv.x, acc[2][0]);
            acc[2][1] = fmaf(av.z, wv.y, acc[2][1]);
            acc[2][2] = fmaf(av.z, wv.z, acc[2][2]);
            acc[2][3] = fmaf(av.z, wv.w, acc[2][3]);
            acc[3][0] = fmaf(av.w, wv.x, acc[3][0]);
            acc[3][1] = fmaf(av.w, wv.y, acc[3][1]);
            acc[3][2] = fmaf(av.w, wv.z, acc[3][2]);
            acc[3][3] = fmaf(av.w, wv.w, acc[3][3]);
        }
        __syncthreads();
    }
#pragma unroll
    for (int i = 0; i < 4; ++i) {
        int r = row0 + ty * 4 + i;
        if (r < NN) {
            ushort4 h = {f2bf(acc[i][0]), f2bf(acc[i][1]), f2bf(acc[i][2]), f2bf(acc[i][3])};
            store_x_plane(Xh, r, tx * 4, h);
        }
    }
}

// ---- scan helpers ----------------------------------------------------------
__device__ inline int wave_incl_scan(int v) {
    int lane = threadIdx.x & 63;
#pragma unroll
    for (int off = 1; off < 64; off <<= 1) {
        int t = __shfl_up(v, off, 64);
        if (lane >= off) v += t;
    }
    return v;
}

// merged 3-phase scan: local exscan -> (last block) partials exscan -> add
// offsets + rsqrt norms. Single kernel, spin-flag global sync. 196 blocks,
// all co-resident (<=256 CUs); flag-setter is by construction the last
// arriver, so no deadlock. Cross-block data (partials) read via atomic loads.
__global__ void scan_fused_kernel(const int* __restrict__ din_cnt,
                                  const int* __restrict__ dout_cnt,
                                  int* __restrict__ row_start,
                                  int* partials,
                                  float* __restrict__ dout_is,
                                  float* __restrict__ din_is,
                                  int* sync) {
    __shared__ int wsum[4];
    __shared__ int sLast;
    int i = blockIdx.x * 256 + threadIdx.x;
    int v = (i < NN) ? din_cnt[i] : 0;
    int lane = threadIdx.x & 63, wid = threadIdx.x >> 6;
    int incl = wave_incl_scan(v);
    if (lane == 63) wsum[wid] = incl;
    __syncthreads();
    if (threadIdx.x == 0) {
        int s = 0;
        for (int w = 0; w < 4; ++w) { int t = wsum[w]; wsum[w] = s; s += t; }
        partials[blockIdx.x] = s;
    }
    __syncthreads();
    int rs_local = incl - v + wsum[wid];
    __threadfence();
    if (threadIdx.x == 0)
        sLast = (atomicAdd(&sync[0], 1) == (int)gridDim.x - 1);
    __syncthreads();   // also protects wsum reuse below
    if (sLast) {
        int nparts = gridDim.x;
        int pv = (threadIdx.x < nparts) ? atomicAdd(&partials[threadIdx.x], 0) : 0;
        int pincl = wave_incl_scan(pv);
        if (lane == 63) wsum[wid] = pincl;
        __syncthreads();
        if (threadIdx.x == 0) {
            int s = 0;
            for (int w = 0; w < 4; ++w) { int t = wsum[w]; wsum[w] = s; s += t; }
            row_start[NN] = NE;
        }
        __syncthreads();
        if (threadIdx.x < nparts) partials[threadIdx.x] = pincl - pv + wsum[wid];
        __threadfence();
        __syncthreads();
        if (threadIdx.x == 0) atomicExch(&sync[1], 1);
    } else {
        if (threadIdx.x == 0) {
            while (atomicAdd(&sync[1], 0) == 0) { __builtin_amdgcn_s_sleep(8); }
        }
        __syncthreads();
        __threadfence();
    }
    if (i < NN) {
        int off = atomicAdd(&partials[blockIdx.x], 0);
        row_start[i] = rs_local + off;
        dout_is[i] = rsqrtf(fmaxf((float)dout_cnt[i], 1.0f));
        din_is[i]  = rsqrtf(fmaxf((float)din_cnt[i], 1.0f));
    }
}

// fill CSR: atomic-free scattered write using precomputed slots
__global__ void csr_fill_kernel(const int* __restrict__ src, const int* __restrict__ dst,
                                const int* __restrict__ row_start, const int* __restrict__ epos,
                                int* __restrict__ csr_src) {
    int e = blockIdx.x * 256 + threadIdx.x;
    if (e < NE) csr_src[row_start[dst[e]] + epos[e]] = src[e];
}

// ---- X = rowscale(A) @ W, register-blocked 64x64 tile (layers 1-3, tail) ---
template <int K, bool OUT_BF16>
__global__ __launch_bounds__(256) void proj_kernel(
    const float* __restrict__ A, int lda,
    const float* __restrict__ W,   // K x 64, row-major
    const float* __restrict__ scale,
    void* __restrict__ Xout) {
    constexpr int KC = 64;
    constexpr int NCHUNK = K / KC;
    __shared__ float sAT[KC * 68];  // [k][row], pitch 68
    __shared__ float sW[KC * 64];   // [k][col]
    float acc[4][4] = {};

    const int t = threadIdx.x;
    const int tx = t & 15;          // col group: cols 4*tx..4*tx+3
    const int ty = t >> 4;          // row group: rows 4*ty..4*ty+3
    const int row0 = blockIdx.x * 64;

    const int srow = t & 63;        // staging: one row per lane
    const int f0 = t >> 6;          // staging float4-col base (0..3)
    int grow = row0 + srow;
    if (grow > NN - 1) grow = NN - 1;   // clamp: loads always in-bounds
    const float* arow = A + (size_t)grow * lda;

    for (int kc = 0; kc < NCHUNK; ++kc) {
#pragma unroll
        for (int it = 0; it < 4; ++it) {
            int k = (f0 + it * 4) * 4;
            float4 a4 = *reinterpret_cast<const float4*>(arow + kc * KC + k);
            sAT[(k + 0) * 68 + srow] = a4.x;
            sAT[(k + 1) * 68 + srow] = a4.y;
            sAT[(k + 2) * 68 + srow] = a4.z;
            sAT[(k + 3) * 68 + srow] = a4.w;
        }
        {
            const float4* wsrc = reinterpret_cast<const float4*>(W + (size_t)kc * KC * 64);
            float4* wdst = reinterpret_cast<float4*>(sW);
#pragma unroll
            for (int it = 0; it < 4; ++it) wdst[t + it * 256] = wsrc[t + it * 256];
        }
        __syncthreads();
#pragma unroll 8
        for (int k = 0; k < KC; ++k) {
            float4 av = *reinterpret_cast<const float4*>(&sAT[k * 68 + ty * 4]);
            float4 wv = *reinterpret_cast<const float4*>(&sW[k * 64 + tx * 4]);
            acc[0][0] = fmaf(av.x, wv.x, acc[0][0]);
            acc[0][1] = fmaf(av.x, wv.y, acc[0][1]);
            acc[0][2] = fmaf(av.x, wv.z, acc[0][2]);
            acc[0][3] = fmaf(av.x, wv.w, acc[0][3]);
            acc[1][0] = fmaf(av.y, wv.x, acc[1][0]);
            acc[1][1] = fmaf(av.y, wv.y, acc[1][1]);
            acc[1][2] = fmaf(av.y, wv.z, acc[1][2]);
            acc[1][3] = fmaf(av.y, wv.w, acc[1][3]);
            acc[2][0] = fmaf(av.z, wv.x, acc[2][0]);
            acc[2][1] = fmaf(av.z, wv.y, acc[2][1]);
            acc[2][2] = fmaf(av.z, wv.z, acc[2][2]);
            acc[2][3] = fmaf(av.z, wv.w, acc[2][3]);
            acc[3][0] = fmaf(av.w, wv.x, acc[3][0]);
            acc[3][1] = fmaf(av.w, wv.y, acc[3][1]);
            acc[3][2] = fmaf(av.w, wv.z, acc[3][2]);
            acc[3][3] = fmaf(av.w, wv.w, acc[3][3]);
        }
        __syncthreads();
    }
#pragma unroll
    for (int i = 0; i < 4; ++i) {
        int r = row0 + ty * 4 + i;
        if (r < NN) {
            float s = scale ? scale[r] : 1.0f;
            float4 o = {acc[i][0] * s, acc[i][1] * s, acc[i][2] * s, acc[i][3] * s};
            if (OUT_BF16) {
                ushort4 h = {f2bf(o.x), f2bf(o.y), f2bf(o.z), f2bf(o.w)};
                store_x_plane((unsigned short*)Xout, r, tx * 4, h);
            } else {
                *reinterpret_cast<float4*>((float*)Xout + (size_t)r * 64 + tx * 4) = o;
            }
        }
    }
}

// ---- pull aggregation, column-split: 2 half-passes, 16 groups x 8 cols -----
// bid/12500 selects the column half (plane); blocks 0..12499 (half A) are
// dispatched before 12500..24999 (half B), so at any instant the live table
// slice is ~3.2MB -> per-XCD L2 resident. One wave per dst row per half.
// lane = group g (lane>>2, 16 rows/instruction in flight) x col-oct
// ((lane&3)*8). uint4 row-slice loads; bf16 unpack via shift/and; f32 accum.
// SSCALE: multiply each neighbor row by sscale[src] (layer 0: dout_is moved
// here from proj0; L2-resident 200KB table).
template <bool SSCALE>
__device__ inline void acc8(float* a, uint4 v, float w) {
    unsigned d0 = v.x, d1 = v.y, d2 = v.z, d3 = v.w;
    if (SSCALE) {
        a[0] = fmaf(__uint_as_float(d0 << 16), w, a[0]);
        a[1] = fmaf(__uint_as_float(d0 & 0xFFFF0000u), w, a[1]);
        a[2] = fmaf(__uint_as_float(d1 << 16), w, a[2]);
        a[3] = fmaf(__uint_as_float(d1 & 0xFFFF0000u), w, a[3]);
        a[4] = fmaf(__uint_as_float(d2 << 16), w, a[4]);
        a[5] = fmaf(__uint_as_float(d2 & 0xFFFF0000u), w, a[5]);
        a[6] = fmaf(__uint_as_float(d3 << 16), w, a[6]);
        a[7] = fmaf(__uint_as_float(d3 & 0xFFFF0000u), w, a[7]);
    } else {
        a[0] += __uint_as_float(d0 << 16);
        a[1] += __uint_as_float(d0 & 0xFFFF0000u);
        a[2] += __uint_as_float(d1 << 16);
        a[3] += __uint_as_float(d1 & 0xFFFF0000u);
        a[4] += __uint_as_float(d2 << 16);
        a[5] += __uint_as_float(d2 & 0xFFFF0000u);
        a[6] += __uint_as_float(d3 << 16);
        a[7] += __uint_as_float(d3 & 0xFFFF0000u);
    }
}

template <bool SSCALE>
__global__ __launch_bounds__(256) void gather16_bf16_kernel(
    const int* __restrict__ row_start, const int* __restrict__ csr_src,
    const unsigned short* __restrict__ Xh,   // 2 planes [NN][32]
    const float* __restrict__ din_is, const float* __restrict__ sscale,
    const float* __restrict__ b, float* __restrict__ out,
    int ldo, int coff, int relu) {
    int bid = blockIdx.x;
    int half = bid / 12500;
    int n = (bid - half * 12500) * 4 + (threadIdx.x >> 6);
    if (n >= NN) return;
    int lane = threadIdx.x & 63;
    int g = lane >> 2;              // neighbor group 0..15
    int c8 = (lane & 3) << 3;       // cols (within half) c8..c8+7
    const unsigned short* Xp = Xh + (size_t)half * ((size_t)NN * 32);
    int s0 = row_start[n], s1 = row_start[n + 1];
    float a[8] = {};
    int i = s0;
    // 32 neighbors/iter: 2 independent 16B row-slice loads in flight per lane
    for (; i + 32 <= s1; i += 32) {
        int ia = csr_src[i + g];
        int ib = csr_src[i + 16 + g];
        uint4 va = *reinterpret_cast<const uint4*>(Xp + (size_t)ia * 32 + c8);
        uint4 vb = *reinterpret_cast<const uint4*>(Xp + (size_t)ib * 32 + c8);
        float wa = SSCALE ? sscale[ia] : 1.0f;
        float wb = SSCALE ? sscale[ib] : 1.0f;
        acc8<SSCALE>(a, va, wa);
        acc8<SSCALE>(a, vb, wb);
    }
    // 16 neighbors/iter
    for (; i + 16 <= s1; i += 16) {
        int ia = csr_src[i + g];
        uint4 va = *reinterpret_cast<const uint4*>(Xp + (size_t)ia * 32 + c8);
        float wa = SSCALE ? sscale[ia] : 1.0f;
        acc8<SSCALE>(a, va, wa);
    }
    // <16 remaining, group-guarded
    if (i + g < s1) {
        int ia = csr_src[i + g];
        uint4 va = *reinterpret_cast<const uint4*>(Xp + (size_t)ia * 32 + c8);
        float wa = SSCALE ? sscale[ia] : 1.0f;
        acc8<SSCALE>(a, va, wa);
    }
    // combine the 16 groups (lanes sharing lane&3 hold the same cols)
#pragma unroll
    for (int off = 4; off < 64; off <<= 1) {
#pragma unroll
        for (int j = 0; j < 8; ++j) a[j] += __shfl_xor(a[j], off, 64);
    }
    if (g == 0) {
        int cb = half * 32 + c8;    // column within the 64-wide layer output
        float4 o0, o1;
        if (relu) {
            float di = din_is[n];
            o0.x = fmaxf(fmaf(a[0], di, b[cb + 0]), 0.0f);
            o0.y = fmaxf(fmaf(a[1], di, b[cb + 1]), 0.0f);
            o0.z = fmaxf(fmaf(a[2], di, b[cb + 2]), 0.0f);
            o0.w = fmaxf(fmaf(a[3], di, b[cb + 3]), 0.0f);
            o1.x = fmaxf(fmaf(a[4], di, b[cb + 4]), 0.0f);
            o1.y = fmaxf(fmaf(a[5], di, b[cb + 5]), 0.0f);
            o1.z = fmaxf(fmaf(a[6], di, b[cb + 6]), 0.0f);
            o1.w = fmaxf(fmaf(a[7], di, b[cb + 7]), 0.0f);
        } else {
            o0.x = a[0] + b[cb + 0];
            o0.y = a[1] + b[cb + 1];
            o0.z = a[2] + b[cb + 2];
            o0.w = a[3] + b[cb + 3];
            o1.x = a[4] + b[cb + 4];
            o1.y = a[5] + b[cb + 5];
            o1.z = a[6] + b[cb + 6];
            o1.w = a[7] + b[cb + 7];
        }
        float* op = out + (size_t)n * ldo + coff + cb;
        *reinterpret_cast<float4*>(op) = o0;
        *reinterpret_cast<float4*>(op + 4) = o1;
    }
}

extern "C" void kernel_launch(void* const* d_in, const int* in_sizes, int n_in,
                              void* d_out, int out_size, void* d_ws, size_t ws_size,
                              hipStream_t stream) {
    const float* feat  = (const float*)d_in[0];
    const int*   src   = (const int*)d_in[1];
    const int*   dst   = (const int*)d_in[2];
    const float* W[4]  = {(const float*)d_in[3], (const float*)d_in[5],
                          (const float*)d_in[7], (const float*)d_in[9]};
    const float* b[4]  = {(const float*)d_in[4], (const float*)d_in[6],
                          (const float*)d_in[8], (const float*)d_in[10]};
    const float* W_mlp = (const float*)d_in[11];
    const float* b_mlp = (const float*)d_in[12];
    float* out = (float*)d_out;

    // workspace layout:
    // C [NN*256 f]  (head transiently reused: dout_cnt [NN i] | cursor [NN i]
    //               | epos [NE i] — all dead before gather-0 writes C)
    // X [NN*64 f]   (bf16 2-plane view aliases the same region)
    // dout_is [NN f] | din_is [NN f] |
    // row_start [NN+1 i] | partials [256 i] | sync [8 i] | csr_src [NE i]
    float* C        = (float*)d_ws;
    int*   dout_cnt = (int*)d_ws;            // NN
    int*   cursor   = dout_cnt + NN;         // NN (doubles as din_cnt)
    int*   epos     = cursor + NN;           // NE
    float* X        = C + (size_t)NN * 256;
    unsigned short* Xh = (unsigned short*)X; // bf16 planes (used disjointly in time)
    float* dout_is  = X + (size_t)NN * 64;
    float* din_is   = dout_is + NN;
    int*   row_start = (int*)(din_is + NN);
    int*   partials  = row_start + NN + 1;
    int*   sync      = partials + 256;
    int*   csr_src   = sync + 8;

    const int NBLK = (NN + 255) / 256;   // 196
    const int GBLK = (NN + 63) / 64;     // 782 (GEMM tiles)
    const int EBLK = (NE + 255) / 256;   // 3125
    const int DEGBLK = (NE + 2047) / 2048;  // 391 degree blocks (8 edges/thread)
    const int FBLK = GBLK + DEGBLK;      // 1173 fused blocks (391 degree @ bid%3==0)

    // zero dout_cnt + cursor (contiguous)
    hipMemsetAsync(dout_cnt, 0, 2 * NN * sizeof(int), stream);

    // fused: degree/cursor atomic pass overlapped with proj0; zeroes sync
    fused_build_proj0_kernel<<<FBLK, 256, 0, stream>>>(feat, W[0], Xh,
                                                       src, dst, dout_cnt, cursor, epos, sync);

    // merged scan: row_start = exscan(cursor) + rsqrt norms, one kernel
    scan_fused_kernel<<<NBLK, 256, 0, stream>>>(cursor, dout_cnt, row_start, partials,
                                                dout_is, din_is, sync);
    csr_fill_kernel<<<EBLK, 256, 0, stream>>>(src, dst, row_start, epos, csr_src);

    // layer 0: X holds UNscaled feat@W0; dout_is applied per-src-row in gather
    gather16_bf16_kernel<true><<<25000, 256, 0, stream>>>(row_start, csr_src, Xh, din_is,
                                                          dout_is, b[0], C, 256, 0, 1);

    // layers 1..3 (K = 64), input = previous slice of C — bf16 X, pre-scaled
    for (int i = 1; i < 4; ++i) {
        proj_kernel<64, true><<<GBLK, 256, 0, stream>>>(C + (i - 1) * 64, 256, W[i], dout_is, Xh);
        gather16_bf16_kernel<false><<<25000, 256, 0, stream>>>(row_start, csr_src, Xh, din_is,
                                                               nullptr, b[i], C, 256, i * 64, 1);
    }

    // tail: P = C @ W_mlp as bf16 (project BEFORE the neighbor-sum; linear),
    // then out = b_mlp + segment_sum(P[src] -> dst)
    proj_kernel<256, true><<<GBLK, 256, 0, stream>>>(C, 256, W_mlp, nullptr, Xh);
    gather16_bf16_kernel<false><<<25000, 256, 0, stream>>>(row_start, csr_src, Xh, nullptr,
                                                           nullptr, b_mlp, out, 64, 0, 0);
}